// Round 2
// baseline (8366.441 us; speedup 1.0000x reference)
//
#include <hip/hip_runtime.h>

// NeighborhoodTransformer: N=20000 nodes, K=32 tokens, D=256, H=8 heads (dh=32), L=3 layers.
// One block (512 thr, 8 waves) per node; fully fused in LDS; bf16 MFMA 16x16x32.
// R2: bf16 master-x, LDS aliasing (P->qb, attn-out/FF-mid->kb) => 69.5 KB LDS => 2 blocks/CU.

#define TOK 32
#define DIM 256
#define NHEAD 8
#define NLAYER 3
#define SCALE 0.17677669529663687f  // 1/sqrt(32)
#define XS 264                      // LDS row stride (bf16 elems): 528B, 16B-aligned, 2-way-bank-free

typedef __bf16 bf16;
typedef __bf16 bf16x8 __attribute__((ext_vector_type(8)));
typedef __bf16 bf16x4 __attribute__((ext_vector_type(4)));
typedef float f32x4 __attribute__((ext_vector_type(4)));

#define MFMA(a, b, c) __builtin_amdgcn_mfma_f32_16x16x32_bf16(a, b, c, 0, 0, 0)

// weight segment offsets inside d_ws (bf16 elems)
#define OFF_WQKV 0
#define OFF_WO   589824   // 3*768*256
#define OFF_W1   786432
#define OFF_W2   983040
#define WTOT     1179648

__device__ __forceinline__ float wred_max16(float v) {
  v = fmaxf(v, __shfl_xor(v, 1)); v = fmaxf(v, __shfl_xor(v, 2));
  v = fmaxf(v, __shfl_xor(v, 4)); v = fmaxf(v, __shfl_xor(v, 8));
  return v;
}
__device__ __forceinline__ float wred_sum16(float v) {
  v += __shfl_xor(v, 1); v += __shfl_xor(v, 2);
  v += __shfl_xor(v, 4); v += __shfl_xor(v, 8);
  return v;
}

// GEMM: out[t][o] = sum_d A[t][d] * W[o][d].  A bf16 LDS (row stride XS), W bf16 global
// row-major [o][256]. Wave computes M-tiles {0,16} x NT N-tiles at obase.
// qlim>0: N-tiles with o<qlim compute only M-tile 0 (last-layer Q).
// mtiles==1: only M-tile 0 everywhere (last-layer out-proj/FF).
template <int NT>
__device__ __forceinline__ void gemm_run(const bf16* __restrict__ A,
                                         const bf16* __restrict__ W, int obase,
                                         int quad, int lc, int mtiles, int qlim,
                                         f32x4 (&acc)[2][NT]) {
#pragma unroll
  for (int m = 0; m < 2; m++)
#pragma unroll
    for (int j = 0; j < NT; j++) acc[m][j] = (f32x4){0.f, 0.f, 0.f, 0.f};

#pragma unroll
  for (int ks = 0; ks < 8; ks++) {
    const int kc = ks * 32 + quad * 8;
    const bf16x8 a0 = *(const bf16x8*)(A + lc * XS + kc);
    bf16x8 a1;
    if (mtiles > 1) a1 = *(const bf16x8*)(A + (16 + lc) * XS + kc);
#pragma unroll
    for (int j = 0; j < NT; j++) {
      const bf16x8 b = *(const bf16x8*)(W + (obase + j * 16 + lc) * DIM + kc);
      acc[0][j] = MFMA(a0, b, acc[0][j]);
      if (mtiles > 1 && (qlim == 0 || (obase + j * 16) >= qlim))
        acc[1][j] = MFMA(a1, b, acc[1][j]);
    }
  }
}

__device__ __forceinline__ void lnorm(bf16 (*xf)[XS], const float* __restrict__ g,
                                      const float* __restrict__ b, int tid) {
  const int t = tid >> 4, i = tid & 15;  // 16 threads per row, 16 contiguous cols each
  const bf16x8 v0 = *(const bf16x8*)&xf[t][i * 16];
  const bf16x8 v1 = *(const bf16x8*)&xf[t][i * 16 + 8];
  float v[16];
#pragma unroll
  for (int j = 0; j < 8; j++) { v[j] = (float)v0[j]; v[8 + j] = (float)v1[j]; }
  float s = 0.f;
#pragma unroll
  for (int j = 0; j < 16; j++) s += v[j];
  s = wred_sum16(s);
  const float mu = s * (1.f / 256.f);
  float q = 0.f;
#pragma unroll
  for (int j = 0; j < 16; j++) { const float d = v[j] - mu; q += d * d; }
  q = wred_sum16(q);
  const float inv = rsqrtf(q * (1.f / 256.f) + 1e-5f);
  f32x4 gv[4], bv[4];
#pragma unroll
  for (int j = 0; j < 4; j++) {
    gv[j] = *(const f32x4*)(g + i * 16 + 4 * j);
    bv[j] = *(const f32x4*)(b + i * 16 + 4 * j);
  }
  bf16x8 o0, o1;
#pragma unroll
  for (int j = 0; j < 8; j++) {
    o0[j] = (bf16)((v[j] - mu) * inv * gv[j >> 2][j & 3] + bv[j >> 2][j & 3]);
    o1[j] = (bf16)((v[8 + j] - mu) * inv * gv[2 + (j >> 2)][j & 3] + bv[2 + (j >> 2)][j & 3]);
  }
  *(bf16x8*)&xf[t][i * 16] = o0;
  *(bf16x8*)&xf[t][i * 16 + 8] = o1;
}

// fp32 -> bf16 weight conversion into workspace (rerun every call: ws is re-poisoned)
__global__ __launch_bounds__(256) void cvtw(const float* __restrict__ wq,
                                            const float* __restrict__ wo,
                                            const float* __restrict__ w1,
                                            const float* __restrict__ w2,
                                            bf16* __restrict__ ws) {
  const int i = (blockIdx.x * 256 + threadIdx.x) * 4;  // 1152*256*4 == WTOT exactly
  float4 v;
  if (i < OFF_WO)       v = *(const float4*)(wq + i);
  else if (i < OFF_W1)  v = *(const float4*)(wo + (i - OFF_WO));
  else if (i < OFF_W2)  v = *(const float4*)(w1 + (i - OFF_W1));
  else                  v = *(const float4*)(w2 + (i - OFF_W2));
  bf16x4 r;
  r[0] = (bf16)v.x; r[1] = (bf16)v.y; r[2] = (bf16)v.z; r[3] = (bf16)v.w;
  *(bf16x4*)(ws + i) = r;
}

__global__ __launch_bounds__(512, 4) void nt_fused(
    const float* __restrict__ h, const float* __restrict__ e, const int* __restrict__ src,
    const bf16* __restrict__ wall, const float* __restrict__ inb,
    const float* __restrict__ outbias, const float* __restrict__ f1b,
    const float* __restrict__ f2b, const float* __restrict__ l1g,
    const float* __restrict__ l1b, const float* __restrict__ l2g,
    const float* __restrict__ l2b, float* __restrict__ out) {
  // 69.5 KB total -> 2 blocks/CU.
  __shared__ __align__(16) bf16 xf[TOK][XS];   // master x (bf16)
  __shared__ __align__(16) bf16 qb[TOK][XS];   // Q; per-head P aliased at own head's columns
  __shared__ __align__(16) bf16 kb[TOK][XS];   // K; attn-out / FF-mid aliased after K consumed
  __shared__ __align__(16) bf16 vt[DIM][40];   // V transposed: vt[c][u]

  const int node = blockIdx.x;
  const int tid = threadIdx.x;
  const int wave = tid >> 6;
  const int lane = tid & 63;
  const int quad = lane >> 4;
  const int lc = lane & 15;

  // stage x = h[src] + e  (16 threads per token row, 16 floats each)
  {
    const int t = tid >> 4;
    const int i = tid & 15;
    const int s = src[node * TOK + t];
    const float* hp = h + (size_t)s * DIM + i * 16;
    const float* ep = e + ((size_t)node * TOK + t) * DIM + i * 16;
    bf16x8 r0, r1;
#pragma unroll
    for (int j = 0; j < 2; j++) {
      const f32x4 a = *(const f32x4*)(hp + 4 * j) + *(const f32x4*)(ep + 4 * j);
      const f32x4 b = *(const f32x4*)(hp + 8 + 4 * j) + *(const f32x4*)(ep + 8 + 4 * j);
      bf16x8& r = j ? r1 : r0;
      (void)r;
    }
    // (compute explicitly to keep it simple)
    const f32x4 a0 = *(const f32x4*)(hp + 0) + *(const f32x4*)(ep + 0);
    const f32x4 a1 = *(const f32x4*)(hp + 4) + *(const f32x4*)(ep + 4);
    const f32x4 a2 = *(const f32x4*)(hp + 8) + *(const f32x4*)(ep + 8);
    const f32x4 a3 = *(const f32x4*)(hp + 12) + *(const f32x4*)(ep + 12);
    bf16x8 w0, w1;
#pragma unroll
    for (int j = 0; j < 4; j++) {
      w0[j] = (bf16)a0[j]; w0[4 + j] = (bf16)a1[j];
      w1[j] = (bf16)a2[j]; w1[4 + j] = (bf16)a3[j];
    }
    *(bf16x8*)&xf[t][i * 16] = w0;
    *(bf16x8*)&xf[t][i * 16 + 8] = w1;
  }
  __syncthreads();

#pragma unroll 1
  for (int layer = 0; layer < NLAYER; layer++) {
    const bool lastl = (layer == NLAYER - 1);  // only token 0 needed downstream
    const bf16* Wq = wall + OFF_WQKV + layer * (768 * 256);
    const bf16* Wo = wall + OFF_WO + layer * 65536;
    const bf16* W1 = wall + OFF_W1 + layer * 65536;
    const bf16* W2 = wall + OFF_W2 + layer * 65536;
    const float* bq = inb + layer * 768;
    const float* bo = outbias + layer * 256;
    const float* b1 = f1b + layer * 256;
    const float* b2 = f2b + layer * 256;
    const float* g1 = l1g + layer * 256;
    const float* be1 = l1b + layer * 256;
    const float* g2 = l2g + layer * 256;
    const float* be2 = l2b + layer * 256;

    // ---- QKV projection: wave owns o in [wave*96, wave*96+96)
    {
      f32x4 acc[2][6];
      gemm_run<6>(&xf[0][0], Wq, wave * 96, quad, lc, 2, lastl ? 256 : 0, acc);
#pragma unroll
      for (int j = 0; j < 6; j++) {
        const int o = wave * 96 + j * 16 + lc;
        const float bias = bq[o];
#pragma unroll
        for (int m = 0; m < 2; m++) {
#pragma unroll
          for (int r = 0; r < 4; r++) {
            const int t = m * 16 + quad * 4 + r;
            const float v = acc[m][j][r] + bias;
            if (o < 256)      qb[t][o] = (bf16)v;
            else if (o < 512) kb[t][o - 256] = (bf16)v;
            else              vt[o - 512][t] = (bf16)v;   // V stored transposed
          }
        }
      }
    }
    __syncthreads();

    // ---- attention: one head per wave (head hh touches only columns [hh*32, hh*32+32))
    {
      const int hh = wave;
      const int nT = lastl ? 1 : 2;  // last layer: only query rows 0..15 (row 0 needed)
      const f32x4 z4 = {0.f, 0.f, 0.f, 0.f};
      bf16x8 aq[2], bk[2];
#pragma unroll
      for (int ti = 0; ti < 2; ti++)
        if (ti < nT) aq[ti] = *(const bf16x8*)&qb[ti * 16 + lc][hh * 32 + quad * 8];
#pragma unroll
      for (int ui = 0; ui < 2; ui++)
        bk[ui] = *(const bf16x8*)&kb[ui * 16 + lc][hh * 32 + quad * 8];
      f32x4 sA[2][2];
#pragma unroll
      for (int ti = 0; ti < 2; ti++)
        if (ti < nT) {
          sA[ti][0] = MFMA(aq[ti], bk[0], z4);
          sA[ti][1] = MFMA(aq[ti], bk[1], z4);
        }
      // softmax; write P into qb at own head's columns (q fragments already in regs)
#pragma unroll
      for (int ti = 0; ti < 2; ti++)
        if (ti < nT) {
#pragma unroll
          for (int r = 0; r < 4; r++) {
            float p0 = sA[ti][0][r] * SCALE;
            float p1 = sA[ti][1][r] * SCALE;
            const float mx = wred_max16(fmaxf(p0, p1));
            p0 = __expf(p0 - mx);
            p1 = __expf(p1 - mx);
            const float rs = 1.f / wred_sum16(p0 + p1);
            const int t = ti * 16 + quad * 4 + r;
            qb[t][hh * 32 + lc] = (bf16)(p0 * rs);
            qb[t][hh * 32 + 16 + lc] = (bf16)(p1 * rs);
          }
        }
      // O = P @ V  (P via LDS round-trip into A-layout; V from vt as B-operand);
      // write O into kb at own head's columns (k fragments already in regs)
      bf16x8 ap[2], bv[2];
#pragma unroll
      for (int ti = 0; ti < 2; ti++)
        if (ti < nT) ap[ti] = *(const bf16x8*)&qb[ti * 16 + lc][hh * 32 + quad * 8];
#pragma unroll
      for (int ci = 0; ci < 2; ci++)
        bv[ci] = *(const bf16x8*)&vt[hh * 32 + ci * 16 + lc][quad * 8];
#pragma unroll
      for (int ti = 0; ti < 2; ti++)
        if (ti < nT) {
#pragma unroll
          for (int ci = 0; ci < 2; ci++) {
            const f32x4 oo = MFMA(ap[ti], bv[ci], z4);
#pragma unroll
            for (int r = 0; r < 4; r++)
              kb[ti * 16 + quad * 4 + r][hh * 32 + ci * 16 + lc] = (bf16)oo[r];
          }
        }
    }
    __syncthreads();

    // ---- out projection (+residual into xf): wave owns o in [wave*32, wave*32+32)
    {
      const int mt = lastl ? 1 : 2;
      f32x4 acc[2][2];
      gemm_run<2>(&kb[0][0], Wo, wave * 32, quad, lc, mt, 0, acc);
#pragma unroll
      for (int j = 0; j < 2; j++) {
        const int o = wave * 32 + j * 16 + lc;
        const float bias = bo[o];
#pragma unroll
        for (int m = 0; m < 2; m++)
          if (m < mt) {
#pragma unroll
            for (int r = 0; r < 4; r++) {
              const int t = m * 16 + quad * 4 + r;
              xf[t][o] = (bf16)((float)xf[t][o] + acc[m][j][r] + bias);
            }
          }
      }
    }
    __syncthreads();
    lnorm(xf, g1, be1, tid);
    __syncthreads();

    // ---- FF1 (relu) -> kb
    {
      const int mt = lastl ? 1 : 2;
      f32x4 acc[2][2];
      gemm_run<2>(&xf[0][0], W1, wave * 32, quad, lc, mt, 0, acc);
#pragma unroll
      for (int j = 0; j < 2; j++) {
        const int o = wave * 32 + j * 16 + lc;
        const float bias = b1[o];
#pragma unroll
        for (int m = 0; m < 2; m++)
          if (m < mt) {
#pragma unroll
            for (int r = 0; r < 4; r++) {
              const int t = m * 16 + quad * 4 + r;
              kb[t][o] = (bf16)fmaxf(acc[m][j][r] + bias, 0.f);
            }
          }
      }
    }
    __syncthreads();

    // ---- FF2 (+residual into xf)
    {
      const int mt = lastl ? 1 : 2;
      f32x4 acc[2][2];
      gemm_run<2>(&kb[0][0], W2, wave * 32, quad, lc, mt, 0, acc);
#pragma unroll
      for (int j = 0; j < 2; j++) {
        const int o = wave * 32 + j * 16 + lc;
        const float bias = b2[o];
#pragma unroll
        for (int m = 0; m < 2; m++)
          if (m < mt) {
#pragma unroll
            for (int r = 0; r < 4; r++) {
              const int t = m * 16 + quad * 4 + r;
              xf[t][o] = (bf16)((float)xf[t][o] + acc[m][j][r] + bias);
            }
          }
      }
    }
    __syncthreads();
    lnorm(xf, g2, be2, tid);
    __syncthreads();
  }

  // output: token 0 row, fp32
  if (tid < 64) {
    const bf16x4 v = *(const bf16x4*)&xf[0][tid * 4];
    f32x4 o;
    o[0] = (float)v[0]; o[1] = (float)v[1]; o[2] = (float)v[2]; o[3] = (float)v[3];
    *(f32x4*)(out + (size_t)node * DIM + tid * 4) = o;
  }
}

extern "C" void kernel_launch(void* const* d_in, const int* in_sizes, int n_in,
                              void* d_out, int out_size, void* d_ws, size_t ws_size,
                              hipStream_t stream) {
  (void)in_sizes; (void)n_in; (void)out_size; (void)ws_size;
  const float* h   = (const float*)d_in[0];
  const float* e   = (const float*)d_in[1];
  const int* src   = (const int*)d_in[2];
  const float* inw = (const float*)d_in[3];
  const float* inb = (const float*)d_in[4];
  const float* ow  = (const float*)d_in[5];
  const float* obi = (const float*)d_in[6];
  const float* f1w = (const float*)d_in[7];
  const float* f1b = (const float*)d_in[8];
  const float* f2w = (const float*)d_in[9];
  const float* f2b = (const float*)d_in[10];
  const float* l1g = (const float*)d_in[11];
  const float* l1b = (const float*)d_in[12];
  const float* l2g = (const float*)d_in[13];
  const float* l2b = (const float*)d_in[14];
  bf16* ws = (bf16*)d_ws;  // needs WTOT*2 = 2,359,296 bytes

  cvtw<<<1152, 256, 0, stream>>>(inw, ow, f1w, f2w, ws);
  nt_fused<<<20000, 512, 0, stream>>>(h, e, src, ws, inb, obi, f1b, f2b,
                                      l1g, l1b, l2g, l2b, (float*)d_out);
}